// Round 8
// baseline (5506.349 us; speedup 1.0000x reference)
//
#include <hip/hip_runtime.h>
#include <stdint.h>

// RNN LM: embed->shift -> 2-layer tanh RNN (T=2048) -> logits vs embedding^T
//         -> log_softmax -> gather at tokens -> sum (scalar out).
//
// k_rnn R9: R8 (single-wave WGs, canary dataflow, no LDS/barriers) with the
// reduce-scatter FIXED: all __shfl_xor ops are lexically unconditional
// (compute both arms, then v_cndmask-select values). R8 put shfls inside
// ternary arms -> divergent convergent-op -> garbage from masked lanes.
//  - L1: 128 WGs x 64 thr, 8 cols; lane owns k in [16l,16l+16), 128 weights,
//    8 per-lane col partials; 8-value convergent reduce-scatter; col=(l>>3)&7;
//    lane l&7==0 stores one dword.
//  - L2: 128 WGs x 64 thr, 4 cols; lane owns 16 h1-k + 8 h2-k (6 quads),
//    96 weights; 4-value convergent reduce-scatter; col=(l>>4)&3; l&15==0
//    stores.
//  - Poll: ONE fused asm block (loads + s_waitcnt vmcnt(0) together).

#define TSEQ 2048
#define NVOCAB 32000
#define DEMB 512
#define DHID 1024
#define CAN 0xFFFFFFFFu

typedef __attribute__((ext_vector_type(8))) short short8;
typedef __attribute__((ext_vector_type(4))) float f32x4;
typedef unsigned long long u64;

__device__ __forceinline__ unsigned short f2bf(float f) {
  union { float f; unsigned u; } v; v.f = f;
  unsigned r = (v.u + 0x7FFFu + ((v.u >> 16) & 1u)) >> 16;
  return (unsigned short)r;
}

// 4 x 16B from one base (offsets 0,16,32,48), single waitcnt (fused, safe).
__device__ __forceinline__ void llc_ld16x4o(const float* p, f32x4& r0, f32x4& r1,
                                            f32x4& r2, f32x4& r3) {
  asm volatile(
      "global_load_dwordx4 %0, %4, off sc0 sc1\n\t"
      "global_load_dwordx4 %1, %4, off offset:16 sc0 sc1\n\t"
      "global_load_dwordx4 %2, %4, off offset:32 sc0 sc1\n\t"
      "global_load_dwordx4 %3, %4, off offset:48 sc0 sc1\n\t"
      "s_waitcnt vmcnt(0)"
      : "=&v"(r0), "=&v"(r1), "=&v"(r2), "=&v"(r3)
      : "v"(p) : "memory");
}

// 4 quads from base A + 2 quads from base B, single waitcnt (fused, safe).
__device__ __forceinline__ void llc_ld_l2(const float* pa, const float* pb,
                                          f32x4& a0, f32x4& a1, f32x4& a2,
                                          f32x4& a3, f32x4& b0, f32x4& b1) {
  asm volatile(
      "global_load_dwordx4 %0, %6, off sc0 sc1\n\t"
      "global_load_dwordx4 %1, %6, off offset:16 sc0 sc1\n\t"
      "global_load_dwordx4 %2, %6, off offset:32 sc0 sc1\n\t"
      "global_load_dwordx4 %3, %6, off offset:48 sc0 sc1\n\t"
      "global_load_dwordx4 %4, %7, off sc0 sc1\n\t"
      "global_load_dwordx4 %5, %7, off offset:16 sc0 sc1\n\t"
      "s_waitcnt vmcnt(0)"
      : "=&v"(a0), "=&v"(a1), "=&v"(a2), "=&v"(a3), "=&v"(b0), "=&v"(b1)
      : "v"(pa), "v"(pb) : "memory");
}

__device__ __forceinline__ void llc_st4(float* p, float v) {
  asm volatile("global_store_dword %0, %1, off sc0 sc1" :: "v"(p), "v"(v) : "memory");
}

__device__ __forceinline__ bool okq4(f32x4 v) {
  return (__float_as_uint(v.x) != CAN) & (__float_as_uint(v.y) != CAN) &
         (__float_as_uint(v.z) != CAN) & (__float_as_uint(v.w) != CAN);
}

__device__ __forceinline__ float tanh_fast(float x) {
  float ax = fabsf(x);
  float e = __expf(ax + ax);
  float t = 1.f - __fdividef(2.f, e + 1.f);
  return (x < 0.f) ? -t : t;
}

// ---------------- init: poison all slots; row 0 = real zeros ----------------
__global__ void k_init(uint4* __restrict__ h1v4, uint4* __restrict__ h2v4) {
  const int n1 = (TSEQ + 1) * DHID / 4;
  const int n2 = (TSEQ + 1) * DEMB / 4;
  uint4 can; can.x = CAN; can.y = CAN; can.z = CAN; can.w = CAN;
  uint4 zer; zer.x = 0u; zer.y = 0u; zer.z = 0u; zer.w = 0u;
  const int stride = gridDim.x * blockDim.x;
  for (int i = blockIdx.x * blockDim.x + threadIdx.x; i < n1 + n2; i += stride) {
    if (i < n1) {
      h1v4[i] = (i < DHID / 4) ? zer : can;
    } else {
      int j = i - n1;
      h2v4[j] = (j < DEMB / 4) ? zer : can;
    }
  }
}

// ---------------- xW1[t][j] = b1[j] + sum_e inputs[t][e]*W1[e][j] ------------
__global__ __launch_bounds__(256) void k_xw1(const int* __restrict__ tok,
                                             const float* __restrict__ emb,
                                             const float* __restrict__ W1,
                                             const float* __restrict__ b1,
                                             float* __restrict__ xW1) {
  __shared__ float in_lds[16 * DEMB];
  const int tid = threadIdx.x;
  const int rb = blockIdx.x >> 2, cb = blockIdx.x & 3;
  const int t0 = rb * 16, j0 = cb * 256;
  for (int idx = tid; idx < 16 * 128; idx += 256) {
    int r = idx >> 7, q = idx & 127;
    int t = t0 + r;
    float4 v;
    if (t == 0) { v.x = 0.f; v.y = 0.f; v.z = 0.f; v.w = 0.f; }
    else        { v = *(const float4*)(emb + (size_t)tok[t - 1] * DEMB + q * 4); }
    *(float4*)&in_lds[r * DEMB + q * 4] = v;
  }
  __syncthreads();
  const int j = j0 + tid;
  float acc[16];
  {
    float bb = b1[j];
#pragma unroll
    for (int r = 0; r < 16; ++r) acc[r] = bb;
  }
  for (int k = 0; k < DEMB; k += 4) {
    const float* wp = W1 + (size_t)k * DHID + j;
    float w0 = wp[0], w1 = wp[DHID], w2 = wp[2 * DHID], w3 = wp[3 * DHID];
#pragma unroll
    for (int r = 0; r < 16; ++r) {
      float4 h = *(const float4*)&in_lds[r * DEMB + k];
      acc[r] += h.x * w0;
      acc[r] += h.y * w1;
      acc[r] += h.z * w2;
      acc[r] += h.w * w3;
    }
  }
#pragma unroll
  for (int r = 0; r < 16; ++r) xW1[(size_t)(t0 + r) * DHID + j] = acc[r];
}

// ---------------- persistent RNN: 256 single-wave WGs ----------------
// WG 0..127: layer1 (8 cols each). WG 128..255: layer2 (4 cols each).
__global__ __launch_bounds__(64, 1) void k_rnn(const float* __restrict__ xW1,
                                               const float* __restrict__ U1,
                                               const float* __restrict__ W2,
                                               const float* __restrict__ U2,
                                               const float* __restrict__ b2,
                                               float* __restrict__ h1v,
                                               float* __restrict__ h2v,
                                               float* __restrict__ h2buf) {
  const int wg = blockIdx.x;
  const int l = threadIdx.x;  // 0..63

  if (wg < 128) {  // ---- layer 1: h1[t] = tanh(xW1[t] + h1[t-1]@U1) ----
    const int c0 = wg * 8;
    // wA[c][kk] = U1[16l+kk][c0+c]
    float wA[8][16];
#pragma unroll
    for (int kk = 0; kk < 16; ++kk) {
      const float* up = U1 + (size_t)(16 * l + kk) * DHID + c0;
#pragma unroll
      for (int c = 0; c < 8; ++c) wA[c][kk] = up[c];
    }
    const int myc = (l >> 3) & 7;                  // this lane's output col
    const bool hi5 = (l & 32) != 0, hi4 = (l & 16) != 0, hi3 = (l & 8) != 0;
    const float* pp = h1v + 16 * l;                // poll row st (st=0 zeros)
    const float* xp = xW1 + c0 + myc;
    float* stp = h1v + DHID + c0 + myc;            // store row st+1 (l&7==0)
    for (int st = 0; st < TSEQ; ++st) {
      float xv = *xp;                              // cached, independent
      f32x4 h0, h1, h2, h3;
      while (true) {
        llc_ld16x4o(pp, h0, h1, h2, h3);
        if (okq4(h0) & okq4(h1) & okq4(h2) & okq4(h3)) break;
      }
      float p[8];
#pragma unroll
      for (int c = 0; c < 8; ++c) {
        float s0 = h0.x * wA[c][0] + h0.y * wA[c][1] + h0.z * wA[c][2] + h0.w * wA[c][3];
        float s1 = h1.x * wA[c][4] + h1.y * wA[c][5] + h1.z * wA[c][6] + h1.w * wA[c][7];
        float s2 = h2.x * wA[c][8] + h2.y * wA[c][9] + h2.z * wA[c][10] + h2.w * wA[c][11];
        float s3 = h3.x * wA[c][12] + h3.y * wA[c][13] + h3.z * wA[c][14] + h3.w * wA[c][15];
        p[c] = (s0 + s1) + (s2 + s3);
      }
      // 8-value reduce-scatter, col=(l>>3)&7. ALL shfls unconditional
      // (compute both arms, select values) — convergent by construction.
      float t0 = p[0] + __shfl_xor(p[0], 32);
      float t1 = p[1] + __shfl_xor(p[1], 32);
      float t2 = p[2] + __shfl_xor(p[2], 32);
      float t3 = p[3] + __shfl_xor(p[3], 32);
      float t4 = p[4] + __shfl_xor(p[4], 32);
      float t5 = p[5] + __shfl_xor(p[5], 32);
      float t6 = p[6] + __shfl_xor(p[6], 32);
      float t7 = p[7] + __shfl_xor(p[7], 32);
      float a0 = hi5 ? t4 : t0;
      float a1 = hi5 ? t5 : t1;
      float a2 = hi5 ? t6 : t2;
      float a3 = hi5 ? t7 : t3;
      float u0 = a0 + __shfl_xor(a0, 16);
      float u1 = a1 + __shfl_xor(a1, 16);
      float u2 = a2 + __shfl_xor(a2, 16);
      float u3 = a3 + __shfl_xor(a3, 16);
      float b0 = hi4 ? u2 : u0;
      float b1 = hi4 ? u3 : u1;
      float v0 = b0 + __shfl_xor(b0, 8);
      float v1 = b1 + __shfl_xor(b1, 8);
      float cc = hi3 ? v1 : v0;
      cc += __shfl_xor(cc, 4);
      cc += __shfl_xor(cc, 2);
      cc += __shfl_xor(cc, 1);
      float hv = tanh_fast(xv + cc);
      if ((l & 7) == 0) llc_st4(stp, hv);
      pp += DHID; xp += DHID; stp += DHID;
    }
  } else {  // ---- layer 2: h2[t] = tanh(h1[t]@W2 + h2[t-1]@U2 + b2) ----
    const int c0 = (wg - 128) * 4;
    // wq[c][kk] = W2[16l+kk][c0+c];  wu[c][kk] = U2[8l+kk][c0+c]
    float wq[4][16], wu[4][8];
#pragma unroll
    for (int kk = 0; kk < 16; ++kk) {
      const float* mp = W2 + (size_t)(16 * l + kk) * DEMB + c0;
#pragma unroll
      for (int c = 0; c < 4; ++c) wq[c][kk] = mp[c];
    }
#pragma unroll
    for (int kk = 0; kk < 8; ++kk) {
      const float* up = U2 + (size_t)(8 * l + kk) * DEMB + c0;
#pragma unroll
      for (int c = 0; c < 4; ++c) wu[c][kk] = up[c];
    }
    const int myc = (l >> 4) & 3;
    const bool hi5 = (l & 32) != 0, hi4 = (l & 16) != 0;
    const float bias = b2[c0 + myc];
    const float* ppA = h1v + DHID + 16 * l;        // h1[t] = row t+1
    const float* ppB = h2v + 8 * l;                // h2[t-1] = row t
    float* stp = h2v + DEMB + c0 + myc;            // row t+1 (l&15==0)
    float* hb = h2buf + DEMB + c0 + myc;
    for (int t = 0; t < TSEQ; ++t) {
      f32x4 a0q, a1q, a2q, a3q, b0q, b1q;
      while (true) {
        llc_ld_l2(ppA, ppB, a0q, a1q, a2q, a3q, b0q, b1q);
        if (okq4(a0q) & okq4(a1q) & okq4(a2q) & okq4(a3q) &
            okq4(b0q) & okq4(b1q)) break;
      }
      float p[4];
#pragma unroll
      for (int c = 0; c < 4; ++c) {
        float s0 = a0q.x * wq[c][0] + a0q.y * wq[c][1] + a0q.z * wq[c][2] + a0q.w * wq[c][3];
        float s1 = a1q.x * wq[c][4] + a1q.y * wq[c][5] + a1q.z * wq[c][6] + a1q.w * wq[c][7];
        float s2 = a2q.x * wq[c][8] + a2q.y * wq[c][9] + a2q.z * wq[c][10] + a2q.w * wq[c][11];
        float s3 = a3q.x * wq[c][12] + a3q.y * wq[c][13] + a3q.z * wq[c][14] + a3q.w * wq[c][15];
        float s4 = b0q.x * wu[c][0] + b0q.y * wu[c][1] + b0q.z * wu[c][2] + b0q.w * wu[c][3];
        float s5 = b1q.x * wu[c][4] + b1q.y * wu[c][5] + b1q.z * wu[c][6] + b1q.w * wu[c][7];
        p[c] = ((s0 + s1) + (s2 + s3)) + (s4 + s5);
      }
      // 4-value reduce-scatter, col=(l>>4)&3. Unconditional shfls.
      float t0 = p[0] + __shfl_xor(p[0], 32);
      float t1 = p[1] + __shfl_xor(p[1], 32);
      float t2 = p[2] + __shfl_xor(p[2], 32);
      float t3 = p[3] + __shfl_xor(p[3], 32);
      float a0 = hi5 ? t2 : t0;
      float a1 = hi5 ? t3 : t1;
      float u0 = a0 + __shfl_xor(a0, 16);
      float u1 = a1 + __shfl_xor(a1, 16);
      float q = hi4 ? u1 : u0;
      q += __shfl_xor(q, 8);
      q += __shfl_xor(q, 4);
      q += __shfl_xor(q, 2);
      q += __shfl_xor(q, 1);
      float hv = tanh_fast(q + bias);
      if ((l & 15) == 0) {
        llc_st4(stp, hv);
        *hb = hv;
      }
      ppA += DHID; ppB += DEMB; stp += DEMB; hb += DEMB;
    }
  }
}

// ---------------- f32 -> bf16 casts (embedding + h2 history) ----------------
__global__ void k_conv(const float* __restrict__ emb, const float* __restrict__ h2f,
                       unsigned short* __restrict__ embB, unsigned short* __restrict__ h2b) {
  const int n1 = NVOCAB * DEMB / 4;
  const int n2 = TSEQ * DEMB / 4;
  const int stride = gridDim.x * blockDim.x;
  for (int i = blockIdx.x * blockDim.x + threadIdx.x; i < n1 + n2; i += stride) {
    float4 v;
    if (i < n1) v = ((const float4*)emb)[i];
    else        v = ((const float4*)h2f)[i - n1];
    ushort4 o;
    o.x = f2bf(v.x); o.y = f2bf(v.y); o.z = f2bf(v.z); o.w = f2bf(v.w);
    if (i < n1) ((ushort4*)embB)[i] = o;
    else        ((ushort4*)h2b)[i - n1] = o;
  }
}

// ---------------- fused logits GEMM + online softmax stats ----------------
__global__ __launch_bounds__(256, 1) void k_logits(const unsigned short* __restrict__ Ab,
                                                   const unsigned short* __restrict__ Bb,
                                                   float* __restrict__ pmax,
                                                   float* __restrict__ psum) {
  extern __shared__ char smem_dyn[];
  unsigned short* As = (unsigned short*)smem_dyn;       // 128*512*2 = 131072 B
  float* sstat = (float*)(smem_dyn + 131072);           // 4*128*2 f32
  const int tid = threadIdx.x;
  const int rb = blockIdx.x >> 4, ch = blockIdx.x & 15;
  const int r0 = rb * 128, v0 = ch * 2000;
  for (int idx = tid; idx < 128 * 64; idx += 256) {
    int row = idx >> 6, kq = idx & 63;
    uint4 v = *(const uint4*)(Ab + (size_t)(r0 + row) * DEMB + kq * 8);
    int byte = (row * 1024 + kq * 16) ^ ((row & 7) << 4);
    *(uint4*)((char*)As + byte) = v;
  }
  __syncthreads();
  const int wv = tid >> 6, lane = tid & 63;
  const int col = lane & 15, kg = lane >> 4;
  f32x4 rmax[8], rsum[8];
#pragma unroll
  for (int t = 0; t < 8; ++t) { rmax[t] = (f32x4)(-3.0e38f); rsum[t] = (f32x4)(0.f); }

  for (int strip = wv; strip < 125; strip += 4) {
    const unsigned short* bp = Bb + (size_t)(v0 + strip * 16 + col) * DEMB + kg * 8;
    f32x4 acc[8];
#pragma unroll
    for (int t = 0; t < 8; ++t) acc[t] = (f32x4)(0.f);
#pragma unroll
    for (int ks = 0; ks < 16; ++ks) {
      short8 bfrag = *(const short8*)(bp + ks * 32);
#pragma unroll
      for (int t = 0; t < 8; ++t) {
        int row = t * 16 + col;
        int byte = (row * 1024 + ks * 64 + kg * 16) ^ ((row & 7) << 4);
        short8 afrag = *(const short8*)((const char*)As + byte);
        acc[t] = __builtin_amdgcn_mfma_f32_16x16x32_bf16(afrag, bfrag, acc[t], 0, 0, 0);
      }
    }
#pragma unroll
    for (int t = 0; t < 8; ++t) {
      f32x4 v = acc[t];
      f32x4 mx = v;
#pragma unroll
      for (int d = 1; d < 16; d <<= 1) {
        mx.x = fmaxf(mx.x, __shfl_xor(mx.x, d));
        mx.y = fmaxf(mx.y, __shfl_xor(mx.y, d));
        mx.z = fmaxf(mx.z, __shfl_xor(mx.z, d));
        mx.w = fmaxf(mx.w, __shfl_xor(mx.w, d));
      }
      f32x4 nm;
      nm.x = fmaxf(rmax[t].x, mx.x);
      nm.y = fmaxf(rmax[t].y, mx.y);
      nm.z = fmaxf(rmax[t].z, mx.z);
      nm.w = fmaxf(rmax[t].w, mx.w);
      f32x4 e;
      e.x = __expf(v.x - nm.x); e.y = __expf(v.y - nm.y);
      e.z = __expf(v.z - nm.z); e.w = __expf(v.w - nm.w);
#pragma unroll
      for (int d = 1; d < 16; d <<= 1) {
        e.x += __shfl_xor(e.x, d);
        e.y += __shfl_xor(e.y, d);
        e.z += __shfl_xor(e.z, d);
        e.w += __shfl_xor(e.w, d);
      }
      rsum[t].x = rsum[t].x * __expf(rmax[t].x - nm.x) + e.x;
      rsum[t].y = rsum[t].y * __expf(rmax[t].y - nm.y) + e.y;
      rsum[t].z = rsum[t].z * __expf(rmax[t].z - nm.z) + e.z;
      rsum[t].w = rsum[t].w * __expf(rmax[t].w - nm.w) + e.w;
      rmax[t] = nm;
    }
  }
  if (col == 0) {
#pragma unroll
    for (int t = 0; t < 8; ++t) {
#pragma unroll
      for (int r = 0; r < 4; ++r) {
        int row = t * 16 + kg * 4 + r;
        sstat[(wv * 128 + row) * 2 + 0] = rmax[t][r];
        sstat[(wv * 128 + row) * 2 + 1] = rsum[t][r];
      }
    }
  }
  __syncthreads();
  if (tid < 128) {
    float m = -3.0e38f, ssum = 0.f;
#pragma unroll
    for (int w2 = 0; w2 < 4; ++w2) {
      float pm = sstat[(w2 * 128 + tid) * 2 + 0];
      float ps = sstat[(w2 * 128 + tid) * 2 + 1];
      float nm2 = fmaxf(m, pm);
      ssum = ssum * __expf(m - nm2) + ps * __expf(pm - nm2);
      m = nm2;
    }
    pmax[(size_t)(r0 + tid) * 16 + ch] = m;
    psum[(size_t)(r0 + tid) * 16 + ch] = ssum;
  }
}

// ---------------- target logit in f32: dot(h2[t], emb[tok[t]]) ----------------
__global__ __launch_bounds__(256) void k_tlogit(const int* __restrict__ tok,
                                                const float* __restrict__ emb,
                                                const float* __restrict__ h2buf,
                                                float* __restrict__ tlog) {
  const int wv = threadIdx.x >> 6, lane = threadIdx.x & 63;
  const int wgid = blockIdx.x * 4 + wv;
  for (int t = wgid; t < TSEQ; t += 128) {
    const float* hp = h2buf + (size_t)(t + 1) * DEMB + lane * 8;
    const float* ep = emb + (size_t)tok[t] * DEMB + lane * 8;
    float4 h0 = *(const float4*)hp, h1v = *(const float4*)(hp + 4);
    float4 e0 = *(const float4*)ep, e1v = *(const float4*)(ep + 4);
    float d = h0.x * e0.x + h0.y * e0.y + h0.z * e0.z + h0.w * e0.w +
              h1v.x * e1v.x + h1v.y * e1v.y + h1v.z * e1v.z + h1v.w * e1v.w;
    for (int m = 1; m < 64; m <<= 1) d += __shfl_xor(d, m);
    if (lane == 0) tlog[t] = d;
  }
}

// ---------------- final: sum_t (tlogit - lse) ----------------
__global__ void k_final(const float* __restrict__ pmax, const float* __restrict__ psum,
                        const float* __restrict__ tlog, float* __restrict__ out) {
  __shared__ float red[4];
  float local = 0.f;
  for (int t = threadIdx.x; t < TSEQ; t += 256) {
    float m = -3.0e38f, s = 0.f;
#pragma unroll
    for (int c = 0; c < 16; ++c) {
      float pm = pmax[t * 16 + c], ps = psum[t * 16 + c];
      float nm = fmaxf(m, pm);
      s = s * __expf(m - nm) + ps * __expf(pm - nm);
      m = nm;
    }
    local += tlog[t] - (m + __logf(s));
  }
  for (int d = 1; d < 64; d <<= 1) local += __shfl_xor(local, d);
  if ((threadIdx.x & 63) == 0) red[threadIdx.x >> 6] = local;
  __syncthreads();
  if (threadIdx.x == 0) out[0] = red[0] + red[1] + red[2] + red[3];
}

// ---------------- host ----------------
extern "C" void kernel_launch(void* const* d_in, const int* in_sizes, int n_in,
                              void* d_out, int out_size, void* d_ws, size_t ws_size,
                              hipStream_t stream) {
  (void)in_sizes; (void)n_in; (void)out_size; (void)ws_size;
  const int*   tok = (const int*)d_in[0];
  const float* emb = (const float*)d_in[1];
  const float* W1  = (const float*)d_in[2];
  const float* U1  = (const float*)d_in[3];
  const float* b1  = (const float*)d_in[4];
  const float* W2  = (const float*)d_in[5];
  const float* U2  = (const float*)d_in[6];
  const float* b2  = (const float*)d_in[7];
  float* out = (float*)d_out;

  char* ws = (char*)d_ws;
  size_t off = 0;
  auto alloc = [&](size_t bytes) {
    char* p = ws + off;
    off = (off + bytes + 255) & ~(size_t)255;
    return p;
  };
  float* h2buf = (float*)alloc((size_t)(TSEQ + 1) * DEMB * 4);
  unsigned short* h2b = (unsigned short*)alloc((size_t)TSEQ * DEMB * 2);
  float* pmax = (float*)alloc((size_t)TSEQ * 16 * 4);
  float* psum = (float*)alloc((size_t)TSEQ * 16 * 4);
  float* tlog = (float*)alloc((size_t)TSEQ * 4);
  // big region: [h2v][h1v][xW1] during k_rnn; embB (32.77MB) overlays from
  // offset 0 afterwards. Safe because k_init re-poisons all h slots at the
  // start of every launch before k_rnn runs.
  size_t sz_h2v = (size_t)(TSEQ + 1) * DEMB * 4;   //  4,196,352
  size_t sz_h1v = (size_t)(TSEQ + 1) * DHID * 4;   //  8,392,704
  size_t sz_xw1 = (size_t)TSEQ * DHID * 4;         //  8,388,608
  size_t sz_embB = (size_t)NVOCAB * DEMB * 2;      // 32,768,000
  size_t big_sz = sz_h2v + sz_h1v + sz_xw1;
  if (sz_embB > big_sz) big_sz = sz_embB;
  char* big = alloc(big_sz);
  float* h2v = (float*)big;
  float* h1v = (float*)(big + sz_h2v);
  float* xW1 = (float*)(big + sz_h2v + sz_h1v);
  unsigned short* embB = (unsigned short*)big;

  k_init<<<dim3(512), dim3(256), 0, stream>>>((uint4*)h1v, (uint4*)h2v);
  k_xw1<<<dim3(512), dim3(256), 0, stream>>>(tok, emb, W1, b1, xW1);
  k_rnn<<<dim3(256), dim3(64), 0, stream>>>(xW1, U1, W2, U2, b2, h1v, h2v, h2buf);
  k_conv<<<dim3(2048), dim3(256), 0, stream>>>(emb, h2buf + DEMB, embB, h2b);
  k_logits<<<dim3(256), dim3(256), 135168, stream>>>(h2b, embB, pmax, psum);
  k_tlogit<<<dim3(32), dim3(256), 0, stream>>>(tok, emb, h2buf, tlog);
  k_final<<<dim3(1), dim3(256), 0, stream>>>(pmax, psum, tlog, out);
}

// Round 10
// 4577.748 us; speedup vs baseline: 1.2029x; 1.2029x over previous
//
#include <hip/hip_runtime.h>
#include <stdint.h>

// RNN LM: embed->shift -> 2-layer tanh RNN (T=2048) -> logits vs embedding^T
//         -> log_softmax -> gather at tokens -> sum (scalar out).
//
// k_rnn R10b: R6 geometry + bf16 h handoff + barrier-free LDS flag combine.
// (R10 with the bfup reference-binding compile error fixed: unpack helpers
// return by value.)
//  - h1v/h2v: [T+1][D] bf16, poisoned 0xFFFF per u16 (dword 0xFFFFFFFF = two
//    NaN bf16 — tanh can never produce it); row 0 = 0x0000 (= +0.0).
//  - Producers pack 2 adjacent cols per dword (full-wave shfl_down, store
//    guarded) -> single dword store per col-pair, sc0 sc1.
//  - Consumers poll dwordx2 (L1) / dwordx2+dword (L2) via ONE fused asm
//    (loads + s_waitcnt vmcnt(0) together). Unpack is exact bit-shift.
//  - Cross-wave combine: no s_barrier. Waves 1-3 write partials to cmb[par]
//    then RELEASE-store flg[par][w]=st+1 and move on; wave 0 ACQUIRE-spins
//    the 3 flags, sums own-reg partial + cmb, tanh, packed store. Stamps
//    monotonic per parity -> no re-init, no races.

#define TSEQ 2048
#define NVOCAB 32000
#define DEMB 512
#define DHID 1024
#define CAN 0xFFFFFFFFu

typedef __attribute__((ext_vector_type(8))) short short8;
typedef __attribute__((ext_vector_type(4))) float f32x4;
typedef __attribute__((ext_vector_type(2))) float f32x2;
typedef __attribute__((ext_vector_type(2))) unsigned u32x2;

__device__ __forceinline__ unsigned short f2bf(float f) {
  union { float f; unsigned u; } v; v.f = f;
  unsigned r = (v.u + 0x7FFFu + ((v.u >> 16) & 1u)) >> 16;
  return (unsigned short)r;
}

__device__ __forceinline__ u32x2 llc_ld8(const unsigned* p) {
  u32x2 r;
  asm volatile("global_load_dwordx2 %0, %1, off sc0 sc1\n\ts_waitcnt vmcnt(0)"
               : "=&v"(r) : "v"(p) : "memory");
  return r;
}

// dwordx2 + dword from two bases, single waitcnt (fused, safe).
__device__ __forceinline__ void llc_ld8_4(const unsigned* pa, const unsigned* pb,
                                          u32x2& a, unsigned& b) {
  asm volatile("global_load_dwordx2 %0, %2, off sc0 sc1\n\t"
               "global_load_dword %1, %3, off sc0 sc1\n\t"
               "s_waitcnt vmcnt(0)"
               : "=&v"(a), "=&v"(b) : "v"(pa), "v"(pb) : "memory");
}

__device__ __forceinline__ void llc_st4u(unsigned* p, unsigned v) {
  asm volatile("global_store_dword %0, %1, off sc0 sc1" :: "v"(p), "v"(v) : "memory");
}

// exact bf16->f32 unpack of a packed dword (lo = even col, hi = odd col)
__device__ __forceinline__ float bflo(unsigned d) {
  return __uint_as_float(d << 16);
}
__device__ __forceinline__ float bfhi(unsigned d) {
  return __uint_as_float(d & 0xFFFF0000u);
}

// rotate right by 1 lane within each 16-lane row (row_ror:1 = 0x121)
__device__ __forceinline__ f32x4 rotq(f32x4 h) {
  f32x4 r;
  r.x = __int_as_float(__builtin_amdgcn_mov_dpp(__float_as_int(h.x), 0x121, 0xf, 0xf, false));
  r.y = __int_as_float(__builtin_amdgcn_mov_dpp(__float_as_int(h.y), 0x121, 0xf, 0xf, false));
  r.z = __int_as_float(__builtin_amdgcn_mov_dpp(__float_as_int(h.z), 0x121, 0xf, 0xf, false));
  r.w = __int_as_float(__builtin_amdgcn_mov_dpp(__float_as_int(h.w), 0x121, 0xf, 0xf, false));
  return r;
}
__device__ __forceinline__ f32x2 rotp(f32x2 h) {
  f32x2 r;
  r.x = __int_as_float(__builtin_amdgcn_mov_dpp(__float_as_int(h.x), 0x121, 0xf, 0xf, false));
  r.y = __int_as_float(__builtin_amdgcn_mov_dpp(__float_as_int(h.y), 0x121, 0xf, 0xf, false));
  return r;
}

__device__ __forceinline__ float tanh_fast(float x) {
  float ax = fabsf(x);
  float e = __expf(ax + ax);
  float t = 1.f - __fdividef(2.f, e + 1.f);
  return (x < 0.f) ? -t : t;
}

// ---------------- init: poison bf16 slots; row 0 = 0x0000 (= 0.0) ----------
__global__ void k_init(uint4* __restrict__ h1q, uint4* __restrict__ h2q) {
  const int n1 = (TSEQ + 1) * DHID * 2 / 16;   // 262272 uint4
  const int n2 = (TSEQ + 1) * DEMB * 2 / 16;   // 131136 uint4
  uint4 can; can.x = CAN; can.y = CAN; can.z = CAN; can.w = CAN;
  uint4 zer; zer.x = 0u; zer.y = 0u; zer.z = 0u; zer.w = 0u;
  const int stride = gridDim.x * blockDim.x;
  for (int i = blockIdx.x * blockDim.x + threadIdx.x; i < n1 + n2; i += stride) {
    if (i < n1) {
      h1q[i] = (i < DHID * 2 / 16) ? zer : can;
    } else {
      int j = i - n1;
      h2q[j] = (j < DEMB * 2 / 16) ? zer : can;
    }
  }
}

// ---------------- xW1[t][j] = b1[j] + sum_e inputs[t][e]*W1[e][j] ------------
__global__ __launch_bounds__(256) void k_xw1(const int* __restrict__ tok,
                                             const float* __restrict__ emb,
                                             const float* __restrict__ W1,
                                             const float* __restrict__ b1,
                                             float* __restrict__ xW1) {
  __shared__ float in_lds[16 * DEMB];
  const int tid = threadIdx.x;
  const int rb = blockIdx.x >> 2, cb = blockIdx.x & 3;
  const int t0 = rb * 16, j0 = cb * 256;
  for (int idx = tid; idx < 16 * 128; idx += 256) {
    int r = idx >> 7, q = idx & 127;
    int t = t0 + r;
    float4 v;
    if (t == 0) { v.x = 0.f; v.y = 0.f; v.z = 0.f; v.w = 0.f; }
    else        { v = *(const float4*)(emb + (size_t)tok[t - 1] * DEMB + q * 4); }
    *(float4*)&in_lds[r * DEMB + q * 4] = v;
  }
  __syncthreads();
  const int j = j0 + tid;
  float acc[16];
  {
    float bb = b1[j];
#pragma unroll
    for (int r = 0; r < 16; ++r) acc[r] = bb;
  }
  for (int k = 0; k < DEMB; k += 4) {
    const float* wp = W1 + (size_t)k * DHID + j;
    float w0 = wp[0], w1 = wp[DHID], w2 = wp[2 * DHID], w3 = wp[3 * DHID];
#pragma unroll
    for (int r = 0; r < 16; ++r) {
      float4 h = *(const float4*)&in_lds[r * DEMB + k];
      acc[r] += h.x * w0;
      acc[r] += h.y * w1;
      acc[r] += h.z * w2;
      acc[r] += h.w * w3;
    }
  }
#pragma unroll
  for (int r = 0; r < 16; ++r) xW1[(size_t)(t0 + r) * DHID + j] = acc[r];
}

// ---------------- persistent RNN ----------------
// 96 WGs x 256 thr. WG 0..63: layer1 (16 cols). WG 64..95: layer2 (16 cols).
// h1v/h2v are bf16 arrays handled as packed dwords (2 cols/dword).
__global__ __launch_bounds__(256, 1) void k_rnn(const float* __restrict__ xW1,
                                                const float* __restrict__ U1,
                                                const float* __restrict__ W2,
                                                const float* __restrict__ U2,
                                                const float* __restrict__ b2,
                                                unsigned* __restrict__ h1v,
                                                unsigned* __restrict__ h2v,
                                                float* __restrict__ h2buf) {
  __shared__ float cmb[2][128];   // [parity][col*8 + wave], waves 1..3 used
  __shared__ int flg[2][4];       // [parity][wave] monotonic step stamps
  const int tid = threadIdx.x;
  const int wg = blockIdx.x;
  const int l = tid & 63, w = tid >> 6;
  const int r = l >> 4, i = l & 15;
  if (tid < 8) flg[tid >> 2][tid & 3] = 0;
  __syncthreads();   // once, before the loop

  if (wg < 64) {  // ---- layer 1: h1[t] = tanh(xW1[t] + h1[t-1]@U1) ----
    const int c0 = wg * 16;
    float wA[64];
#pragma unroll
    for (int j = 0; j < 16; ++j) {
      int sl = (i - j) & 15;
      const float* up = U1 + (size_t)(256 * w + 64 * r + 4 * sl) * DHID + c0 + i;
#pragma unroll
      for (int e = 0; e < 4; ++e) wA[4 * j + e] = up[(size_t)e * DHID];
    }
    const unsigned* pp = h1v + 2 * tid;           // poll row st (dwords)
    const float* xp = xW1 + c0 + (tid & 15);
    unsigned* stp = h1v + (DHID / 2) + ((c0 + l) >> 1);  // row st+1 (even l<16)
    for (int st = 0; st < TSEQ; ++st) {
      float xv = *xp;                             // cached, independent
      u32x2 d;
      while (true) { d = llc_ld8(pp); if ((d.x != CAN) & (d.y != CAN)) break; }
      f32x4 h;
      h.x = bflo(d.x); h.y = bfhi(d.x);
      h.z = bflo(d.y); h.w = bfhi(d.y);
      f32x4 ac = (f32x4)(0.f);
#pragma unroll
      for (int j = 0; j < 16; ++j) {
        ac.x += h.x * wA[4 * j + 0];
        ac.y += h.y * wA[4 * j + 1];
        ac.z += h.z * wA[4 * j + 2];
        ac.w += h.w * wA[4 * j + 3];
        if (j < 15) h = rotq(h);
      }
      float a = (ac.x + ac.y) + (ac.z + ac.w);
      a += __shfl_xor(a, 16);
      a += __shfl_xor(a, 32);
      const int par = st & 1;
      if (w > 0) {                                // producer waves: post & go
        if (l < 16) cmb[par][l * 8 + w] = a;
        if (l == 0)
          __hip_atomic_store(&flg[par][w], st + 1, __ATOMIC_RELEASE,
                             __HIP_MEMORY_SCOPE_WORKGROUP);
      } else {                                    // wave 0: combine & publish
        while (true) {
          int f1 = __hip_atomic_load(&flg[par][1], __ATOMIC_ACQUIRE, __HIP_MEMORY_SCOPE_WORKGROUP);
          int f2 = __hip_atomic_load(&flg[par][2], __ATOMIC_ACQUIRE, __HIP_MEMORY_SCOPE_WORKGROUP);
          int f3 = __hip_atomic_load(&flg[par][3], __ATOMIC_ACQUIRE, __HIP_MEMORY_SCOPE_WORKGROUP);
          if ((f1 == st + 1) & (f2 == st + 1) & (f3 == st + 1)) break;
        }
        f32x4 c4 = *(const f32x4*)&cmb[par][(l & 15) * 8];
        float s = a + ((c4.y + c4.z) + c4.w);
        float hv = tanh_fast(xv + s);
        float hv2 = __shfl_down(hv, 1);           // full-wave, convergent
        if ((l & 1) == 0 && l < 16) {
          unsigned pk = (unsigned)f2bf(hv) | ((unsigned)f2bf(hv2) << 16);
          llc_st4u(stp, pk);
        }
      }
      pp += DHID / 2; xp += DHID; stp += DHID / 2;
    }
  } else {  // ---- layer 2: h2[t] = tanh(h1[t]@W2 + h2[t-1]@U2 + b2) ----
    const int c0 = (wg - 64) * 16;
    float wq[64], wp[32];
#pragma unroll
    for (int j = 0; j < 16; ++j) {
      int sl = (i - j) & 15;
      const float* m = W2 + (size_t)(256 * w + 64 * r + 4 * sl) * DEMB + c0 + i;
#pragma unroll
      for (int e = 0; e < 4; ++e) wq[4 * j + e] = m[(size_t)e * DEMB];
      const float* u = U2 + (size_t)(128 * w + 32 * r + 2 * sl) * DEMB + c0 + i;
      wp[2 * j + 0] = u[0];
      wp[2 * j + 1] = u[DEMB];
    }
    const float bias = b2[c0 + (tid & 15)];
    const unsigned* ppA = h1v + (DHID / 2) + 128 * w + 32 * r + 2 * i;  // h1[t]
    const unsigned* ppB = h2v + 64 * w + 16 * r + i;                    // h2[t-1]
    unsigned* stp = h2v + (DEMB / 2) + ((c0 + l) >> 1);   // row t+1 (even l<16)
    float* hb = h2buf + DEMB + c0 + l;                    // f32 history (l<16)
    for (int t = 0; t < TSEQ; ++t) {
      u32x2 dA; unsigned dB;
      while (true) {
        llc_ld8_4(ppA, ppB, dA, dB);
        if ((dA.x != CAN) & (dA.y != CAN) & (dB != CAN)) break;
      }
      f32x4 hq; f32x2 hp2;
      hq.x = bflo(dA.x); hq.y = bfhi(dA.x);
      hq.z = bflo(dA.y); hq.w = bfhi(dA.y);
      hp2.x = bflo(dB);  hp2.y = bfhi(dB);
      f32x4 aq = (f32x4)(0.f);
      f32x2 ap = (f32x2)(0.f);
#pragma unroll
      for (int j = 0; j < 16; ++j) {
        aq.x += hq.x * wq[4 * j + 0];
        aq.y += hq.y * wq[4 * j + 1];
        aq.z += hq.z * wq[4 * j + 2];
        aq.w += hq.w * wq[4 * j + 3];
        ap.x += hp2.x * wp[2 * j + 0];
        ap.y += hp2.y * wp[2 * j + 1];
        if (j < 15) { hq = rotq(hq); hp2 = rotp(hp2); }
      }
      float a = ((aq.x + aq.y) + (aq.z + aq.w)) + (ap.x + ap.y);
      a += __shfl_xor(a, 16);
      a += __shfl_xor(a, 32);
      const int par = t & 1;
      if (w > 0) {
        if (l < 16) cmb[par][l * 8 + w] = a;
        if (l == 0)
          __hip_atomic_store(&flg[par][w], t + 1, __ATOMIC_RELEASE,
                             __HIP_MEMORY_SCOPE_WORKGROUP);
      } else {
        while (true) {
          int f1 = __hip_atomic_load(&flg[par][1], __ATOMIC_ACQUIRE, __HIP_MEMORY_SCOPE_WORKGROUP);
          int f2 = __hip_atomic_load(&flg[par][2], __ATOMIC_ACQUIRE, __HIP_MEMORY_SCOPE_WORKGROUP);
          int f3 = __hip_atomic_load(&flg[par][3], __ATOMIC_ACQUIRE, __HIP_MEMORY_SCOPE_WORKGROUP);
          if ((f1 == t + 1) & (f2 == t + 1) & (f3 == t + 1)) break;
        }
        f32x4 c4 = *(const f32x4*)&cmb[par][(l & 15) * 8];
        float s = a + ((c4.y + c4.z) + c4.w);
        float hv = tanh_fast(s + bias);
        float hv2 = __shfl_down(hv, 1);           // full-wave, convergent
        if (l < 16) *hb = hv;                     // f32 history for logits path
        if ((l & 1) == 0 && l < 16) {
          unsigned pk = (unsigned)f2bf(hv) | ((unsigned)f2bf(hv2) << 16);
          llc_st4u(stp, pk);
        }
      }
      ppA += DHID / 2; ppB += DEMB / 2; stp += DEMB / 2; hb += DEMB;
    }
  }
}

// ---------------- f32 -> bf16 casts (embedding + h2 history) ----------------
__global__ void k_conv(const float* __restrict__ emb, const float* __restrict__ h2f,
                       unsigned short* __restrict__ embB, unsigned short* __restrict__ h2b) {
  const int n1 = NVOCAB * DEMB / 4;
  const int n2 = TSEQ * DEMB / 4;
  const int stride = gridDim.x * blockDim.x;
  for (int i = blockIdx.x * blockDim.x + threadIdx.x; i < n1 + n2; i += stride) {
    float4 v;
    if (i < n1) v = ((const float4*)emb)[i];
    else        v = ((const float4*)h2f)[i - n1];
    ushort4 o;
    o.x = f2bf(v.x); o.y = f2bf(v.y); o.z = f2bf(v.z); o.w = f2bf(v.w);
    if (i < n1) ((ushort4*)embB)[i] = o;
    else        ((ushort4*)h2b)[i - n1] = o;
  }
}

// ---------------- fused logits GEMM + online softmax stats ----------------
__global__ __launch_bounds__(256, 1) void k_logits(const unsigned short* __restrict__ Ab,
                                                   const unsigned short* __restrict__ Bb,
                                                   float* __restrict__ pmax,
                                                   float* __restrict__ psum) {
  extern __shared__ char smem_dyn[];
  unsigned short* As = (unsigned short*)smem_dyn;       // 128*512*2 = 131072 B
  float* sstat = (float*)(smem_dyn + 131072);           // 4*128*2 f32
  const int tid = threadIdx.x;
  const int rb = blockIdx.x >> 4, ch = blockIdx.x & 15;
  const int r0 = rb * 128, v0 = ch * 2000;
  for (int idx = tid; idx < 128 * 64; idx += 256) {
    int row = idx >> 6, kq = idx & 63;
    uint4 v = *(const uint4*)(Ab + (size_t)(r0 + row) * DEMB + kq * 8);
    int byte = (row * 1024 + kq * 16) ^ ((row & 7) << 4);
    *(uint4*)((char*)As + byte) = v;
  }
  __syncthreads();
  const int wv = tid >> 6, lane = tid & 63;
  const int col = lane & 15, kg = lane >> 4;
  f32x4 rmax[8], rsum[8];
#pragma unroll
  for (int t = 0; t < 8; ++t) { rmax[t] = (f32x4)(-3.0e38f); rsum[t] = (f32x4)(0.f); }

  for (int strip = wv; strip < 125; strip += 4) {
    const unsigned short* bp = Bb + (size_t)(v0 + strip * 16 + col) * DEMB + kg * 8;
    f32x4 acc[8];
#pragma unroll
    for (int t = 0; t < 8; ++t) acc[t] = (f32x4)(0.f);
#pragma unroll
    for (int ks = 0; ks < 16; ++ks) {
      short8 bfrag = *(const short8*)(bp + ks * 32);
#pragma unroll
      for (int t = 0; t < 8; ++t) {
        int row = t * 16 + col;
        int byte = (row * 1024 + ks * 64 + kg * 16) ^ ((row & 7) << 4);
        short8 afrag = *(const short8*)((const char*)As + byte);
        acc[t] = __builtin_amdgcn_mfma_f32_16x16x32_bf16(afrag, bfrag, acc[t], 0, 0, 0);
      }
    }
#pragma unroll
    for (int t = 0; t < 8; ++t) {
      f32x4 v = acc[t];
      f32x4 mx = v;
#pragma unroll
      for (int d = 1; d < 16; d <<= 1) {
        mx.x = fmaxf(mx.x, __shfl_xor(mx.x, d));
        mx.y = fmaxf(mx.y, __shfl_xor(mx.y, d));
        mx.z = fmaxf(mx.z, __shfl_xor(mx.z, d));
        mx.w = fmaxf(mx.w, __shfl_xor(mx.w, d));
      }
      f32x4 nm;
      nm.x = fmaxf(rmax[t].x, mx.x);
      nm.y = fmaxf(rmax[t].y, mx.y);
      nm.z = fmaxf(rmax[t].z, mx.z);
      nm.w = fmaxf(rmax[t].w, mx.w);
      f32x4 e;
      e.x = __expf(v.x - nm.x); e.y = __expf(v.y - nm.y);
      e.z = __expf(v.z - nm.z); e.w = __expf(v.w - nm.w);
#pragma unroll
      for (int d = 1; d < 16; d <<= 1) {
        e.x += __shfl_xor(e.x, d);
        e.y += __shfl_xor(e.y, d);
        e.z += __shfl_xor(e.z, d);
        e.w += __shfl_xor(e.w, d);
      }
      rsum[t].x = rsum[t].x * __expf(rmax[t].x - nm.x) + e.x;
      rsum[t].y = rsum[t].y * __expf(rmax[t].y - nm.y) + e.y;
      rsum[t].z = rsum[t].z * __expf(rmax[t].z - nm.z) + e.z;
      rsum[t].w = rsum[t].w * __expf(rmax[t].w - nm.w) + e.w;
      rmax[t] = nm;
    }
  }
  if (col == 0) {
#pragma unroll
    for (int t = 0; t < 8; ++t) {
#pragma unroll
      for (int r = 0; r < 4; ++r) {
        int row = t * 16 + kg * 4 + r;
        sstat[(wv * 128 + row) * 2 + 0] = rmax[t][r];
        sstat[(wv * 128 + row) * 2 + 1] = rsum[t][r];
      }
    }
  }
  __syncthreads();
  if (tid < 128) {
    float m = -3.0e38f, ssum = 0.f;
#pragma unroll
    for (int w2 = 0; w2 < 4; ++w2) {
      float pm = sstat[(w2 * 128 + tid) * 2 + 0];
      float ps = sstat[(w2 * 128 + tid) * 2 + 1];
      float nm2 = fmaxf(m, pm);
      ssum = ssum * __expf(m - nm2) + ps * __expf(pm - nm2);
      m = nm2;
    }
    pmax[(size_t)(r0 + tid) * 16 + ch] = m;
    psum[(size_t)(r0 + tid) * 16 + ch] = ssum;
  }
}

// ---------------- target logit in f32: dot(h2[t], emb[tok[t]]) ----------------
__global__ __launch_bounds__(256) void k_tlogit(const int* __restrict__ tok,
                                                const float* __restrict__ emb,
                                                const float* __restrict__ h2buf,
                                                float* __restrict__ tlog) {
  const int wv = threadIdx.x >> 6, lane = threadIdx.x & 63;
  const int wgid = blockIdx.x * 4 + wv;
  for (int t = wgid; t < TSEQ; t += 128) {
    const float* hp = h2buf + (size_t)(t + 1) * DEMB + lane * 8;
    const float* ep = emb + (size_t)tok[t] * DEMB + lane * 8;
    float4 h0 = *(const float4*)hp, h1v = *(const float4*)(hp + 4);
    float4 e0 = *(const float4*)ep, e1v = *(const float4*)(ep + 4);
    float d = h0.x * e0.x + h0.y * e0.y + h0.z * e0.z + h0.w * e0.w +
              h1v.x * e1v.x + h1v.y * e1v.y + h1v.z * e1v.z + h1v.w * e1v.w;
    for (int m = 1; m < 64; m <<= 1) d += __shfl_xor(d, m);
    if (lane == 0) tlog[t] = d;
  }
}

// ---------------- final: sum_t (tlogit - lse) ----------------
__global__ void k_final(const float* __restrict__ pmax, const float* __restrict__ psum,
                        const float* __restrict__ tlog, float* __restrict__ out) {
  __shared__ float red[4];
  float local = 0.f;
  for (int t = threadIdx.x; t < TSEQ; t += 256) {
    float m = -3.0e38f, s = 0.f;
#pragma unroll
    for (int c = 0; c < 16; ++c) {
      float pm = pmax[t * 16 + c], ps = psum[t * 16 + c];
      float nm = fmaxf(m, pm);
      s = s * __expf(m - nm) + ps * __expf(pm - nm);
      m = nm;
    }
    local += tlog[t] - (m + __logf(s));
  }
  for (int d = 1; d < 64; d <<= 1) local += __shfl_xor(local, d);
  if ((threadIdx.x & 63) == 0) red[threadIdx.x >> 6] = local;
  __syncthreads();
  if (threadIdx.x == 0) out[0] = red[0] + red[1] + red[2] + red[3];
}

// ---------------- host ----------------
extern "C" void kernel_launch(void* const* d_in, const int* in_sizes, int n_in,
                              void* d_out, int out_size, void* d_ws, size_t ws_size,
                              hipStream_t stream) {
  (void)in_sizes; (void)n_in; (void)out_size; (void)ws_size;
  const int*   tok = (const int*)d_in[0];
  const float* emb = (const float*)d_in[1];
  const float* W1  = (const float*)d_in[2];
  const float* U1  = (const float*)d_in[3];
  const float* b1  = (const float*)d_in[4];
  const float* W2  = (const float*)d_in[5];
  const float* U2  = (const float*)d_in[6];
  const float* b2  = (const float*)d_in[7];
  float* out = (float*)d_out;

  char* ws = (char*)d_ws;
  size_t off = 0;
  auto alloc = [&](size_t bytes) {
    char* p = ws + off;
    off = (off + bytes + 255) & ~(size_t)255;
    return p;
  };
  float* h2buf = (float*)alloc((size_t)(TSEQ + 1) * DEMB * 4);
  unsigned short* h2b = (unsigned short*)alloc((size_t)TSEQ * DEMB * 2);
  float* pmax = (float*)alloc((size_t)TSEQ * 16 * 4);
  float* psum = (float*)alloc((size_t)TSEQ * 16 * 4);
  float* tlog = (float*)alloc((size_t)TSEQ * 4);
  // big region: [h2v][h1v][xW1] during k_rnn (bf16 h arrays); embB (32.77MB)
  // overlays from offset 0 afterwards. Safe because k_init re-poisons all h
  // slots at the start of every launch before k_rnn runs.
  size_t sz_h2v = (size_t)(TSEQ + 1) * DEMB * 2;   //  2,098,176
  size_t sz_h1v = (size_t)(TSEQ + 1) * DHID * 2;   //  4,196,352
  size_t sz_xw1 = (size_t)TSEQ * DHID * 4;         //  8,388,608
  size_t sz_embB = (size_t)NVOCAB * DEMB * 2;      // 32,768,000
  size_t big_sz = sz_h2v + sz_h1v + sz_xw1;
  if (sz_embB > big_sz) big_sz = sz_embB;
  char* big = alloc(big_sz);
  unsigned* h2v = (unsigned*)big;
  unsigned* h1v = (unsigned*)(big + sz_h2v);
  float* xW1 = (float*)(big + sz_h2v + sz_h1v);
  unsigned short* embB = (unsigned short*)big;

  k_init<<<dim3(512), dim3(256), 0, stream>>>((uint4*)h1v, (uint4*)h2v);
  k_xw1<<<dim3(512), dim3(256), 0, stream>>>(tok, emb, W1, b1, xW1);
  k_rnn<<<dim3(96), dim3(256), 0, stream>>>(xW1, U1, W2, U2, b2, h1v, h2v, h2buf);
  k_conv<<<dim3(2048), dim3(256), 0, stream>>>(emb, h2buf + DEMB, embB, h2b);
  k_logits<<<dim3(256), dim3(256), 135168, stream>>>(h2b, embB, pmax, psum);
  k_tlogit<<<dim3(32), dim3(256), 0, stream>>>(tok, emb, h2buf, tlog);
  k_final<<<dim3(1), dim3(256), 0, stream>>>(pmax, psum, tlog, out);
}